// Round 11
// baseline (8132.973 us; speedup 1.0000x reference)
//
#include <hip/hip_runtime.h>

// HighwayLayerDiscrete: 256-step recurrent highway net, batch 64, units 1024.
// Reference per step: p0 h=lrelu(y@w_y+xe@w_x+b_in); p1/p2 h=lrelu(h@w_h+b_h);
// p3 y += h@w_out + b_out; out[:,t,:]=y.
//
// R18 = R17 (6.99 ms, 3-phase refold, no spill) with phase C's two GEMM
// passes FUSED into one loop. R17 post-mortem: A/B ~6.1us but C ~15us --
// pass-2's inline w_ow loads are ~600cy LLC RTs exposed after a barrier with
// nothing to hide under, plus an extra barrier+reduce round. Fusion: each
// q-iteration does the y-half from register-resident wreg (2100cy of FMA
// slack) while the w_ow loads for the z-half pipeline in flight underneath.
// red2 doubled ([y|z] partials, LDS 104.5KB < 160; >64KB static proven by
// R17's 69.5KB) -> ONE barrier+finalize for both sums; A-tile LDS reads
// halved vs R17's two passes. __launch_bounds__(512) (cap 256) for the
// +16-reg accz; SINGLE wreg reload site kept (R16 lesson: a second reload
// site forces wreg live-doubling -> 113GB scratch spill).
// Algebra (validated R14/R16/R17): z_t := y_t @ w_y private state;
//   z' = z + h2@w_ow + b_ow (w_ow = w_out@w_y, b_ow = b_out@w_y, prologue);
//   h0' = lrelu(z' + xp[t+1]) elementwise-private; y' = y + h2@w_out + b_out
//   with y = 1 reg/thread, never staged. 3 exchanges/step (was 4).
// Carried R13 wins: per-producer flag stores + coalesced 32-lane poll
// (bounded); finalize operands prefetched; out-store deferred past flag post.
// Carried invariants: 256 coop blocks x 512 thr (R4); no cross-WG split-K
// (R2/R3); no fences (R1); sc1/LLC only (R9: sc0 deadlocks); release =
// waitcnt0+barrier+flag store; acquire = poll+barrier+clobber; LDS skew
// injective (R5); red2 de-aliased from a_s.

constexpr int B = 64, T = 256, U = 1024, E = 512;
constexpr int BU = B * U;     // 65536
constexpr int APITCH = 1156;  // A-row pitch (1024 + 36-skew; ==4 mod 8)
constexpr int RZOFF = 8448;   // red2 z-partials offset (32*264)

#define LRELU(v) ((v) > 0.f ? (v) : 0.2f * (v))

using f4 = float __attribute__((ext_vector_type(4)));

__device__ __forceinline__ unsigned long long llc_load64(const float* p) {
  return __hip_atomic_load((const unsigned long long*)p, __ATOMIC_RELAXED,
                           __HIP_MEMORY_SCOPE_AGENT);
}
__device__ __forceinline__ void llc_store(float* p, float v) {
  __hip_atomic_store(p, v, __ATOMIC_RELAXED, __HIP_MEMORY_SCOPE_AGENT);
}
__device__ __forceinline__ unsigned llc_flag(const unsigned* p) {
  return __hip_atomic_load(p, __ATOMIC_RELAXED, __HIP_MEMORY_SCOPE_AGENT);
}
__device__ __forceinline__ void llc_flag_store(unsigned* p, unsigned v) {
  __hip_atomic_store(p, v, __ATOMIC_RELAXED, __HIP_MEMORY_SCOPE_AGENT);
}

// -------- init: zero flags and the k_vecs atomic accumulators --------
__global__ void k_init(unsigned* __restrict__ flags, float* __restrict__ z0,
                       float* __restrict__ b_ow) {
  int i = blockIdx.x * 256 + threadIdx.x;  // grid 4 -> 1024
  if (i < 1024) {
    flags[i] = 0u;
    z0[i] = 0.f;
    b_ow[i] = 0.f;
  }
}

// ------- xproj[t*64+n][u] = emb[x[n][t]] @ w_x + b_in (R2/R3-proven) -------
__global__ __launch_bounds__(256) void k_xproj(
    const int* __restrict__ x, const float* __restrict__ emb,
    const float* __restrict__ w_x, const float* __restrict__ b_in,
    float* __restrict__ xp) {
  __shared__ float a_s[64][36];
  __shared__ float w_s[32][64];
  __shared__ int idxs[64];
  const int tid = threadIdx.x;
  const int m0 = blockIdx.x * 64;
  const int c0 = blockIdx.y * 64;
  if (tid < 64) {
    int m = m0 + tid;
    idxs[tid] = x[(m & 63) * T + (m >> 6)];  // x[n][t], row m = t*64+n
  }
  __syncthreads();
  const int rq = tid >> 4, cq = tid & 15;
  float acc[4][4] = {};
  for (int k0 = 0; k0 < E; k0 += 32) {
#pragma unroll
    for (int rep = 0; rep < 8; ++rep) {
      int e = rep * 256 + tid;
      int r = e >> 5, k = e & 31;
      a_s[r][k] = emb[(size_t)idxs[r] * E + k0 + k];
    }
#pragma unroll
    for (int rep = 0; rep < 2; ++rep) {
      int e = rep * 256 + tid;
      int kr = e >> 4, q = e & 15;
      *(float4*)&w_s[kr][4 * q] =
          *(const float4*)(w_x + (size_t)(k0 + kr) * U + c0 + 4 * q);
    }
    __syncthreads();
#pragma unroll
    for (int kc = 0; kc < 32; kc += 4) {
      float4 a4[4], w4[4];
#pragma unroll
      for (int i = 0; i < 4; ++i) a4[i] = *(const float4*)&a_s[4 * rq + i][kc];
#pragma unroll
      for (int kk = 0; kk < 4; ++kk)
        w4[kk] = *(const float4*)&w_s[kc + kk][4 * cq];
#pragma unroll
      for (int i = 0; i < 4; ++i) {
        const float av[4] = {a4[i].x, a4[i].y, a4[i].z, a4[i].w};
#pragma unroll
        for (int kk = 0; kk < 4; ++kk) {
          acc[i][0] += av[kk] * w4[kk].x;
          acc[i][1] += av[kk] * w4[kk].y;
          acc[i][2] += av[kk] * w4[kk].z;
          acc[i][3] += av[kk] * w4[kk].w;
        }
      }
    }
    __syncthreads();
  }
  const float4 bb = *(const float4*)(b_in + c0 + 4 * cq);
  const float bv[4] = {bb.x, bb.y, bb.z, bb.w};
#pragma unroll
  for (int i = 0; i < 4; ++i) {
    float4 o;
    o.x = acc[i][0] + bv[0];
    o.y = acc[i][1] + bv[1];
    o.z = acc[i][2] + bv[2];
    o.w = acc[i][3] + bv[3];
    *(float4*)(xp + (size_t)(m0 + 4 * rq + i) * U + c0 + 4 * cq) = o;
  }
}

// -------- w_ow[k][u] = sum_j w_out[k][j] * w_y[j][u]  (same tile GEMM) -----
__global__ __launch_bounds__(256) void k_wcat(const float* __restrict__ wo,
                                              const float* __restrict__ wy,
                                              float* __restrict__ wow) {
  __shared__ float a_s[64][36];
  __shared__ float w_s[32][64];
  const int tid = threadIdx.x;
  const int m0 = blockIdx.x * 64;
  const int c0 = blockIdx.y * 64;
  const int rq = tid >> 4, cq = tid & 15;
  float acc[4][4] = {};
  for (int k0 = 0; k0 < U; k0 += 32) {
#pragma unroll
    for (int rep = 0; rep < 8; ++rep) {
      int e = rep * 256 + tid;
      int r = e >> 5, k = e & 31;
      a_s[r][k] = wo[(size_t)(m0 + r) * U + k0 + k];
    }
#pragma unroll
    for (int rep = 0; rep < 2; ++rep) {
      int e = rep * 256 + tid;
      int kr = e >> 4, q = e & 15;
      *(float4*)&w_s[kr][4 * q] =
          *(const float4*)(wy + (size_t)(k0 + kr) * U + c0 + 4 * q);
    }
    __syncthreads();
#pragma unroll
    for (int kc = 0; kc < 32; kc += 4) {
      float4 a4[4], w4[4];
#pragma unroll
      for (int i = 0; i < 4; ++i) a4[i] = *(const float4*)&a_s[4 * rq + i][kc];
#pragma unroll
      for (int kk = 0; kk < 4; ++kk)
        w4[kk] = *(const float4*)&w_s[kc + kk][4 * cq];
#pragma unroll
      for (int i = 0; i < 4; ++i) {
        const float av[4] = {a4[i].x, a4[i].y, a4[i].z, a4[i].w};
#pragma unroll
        for (int kk = 0; kk < 4; ++kk) {
          acc[i][0] += av[kk] * w4[kk].x;
          acc[i][1] += av[kk] * w4[kk].y;
          acc[i][2] += av[kk] * w4[kk].z;
          acc[i][3] += av[kk] * w4[kk].w;
        }
      }
    }
    __syncthreads();
  }
#pragma unroll
  for (int i = 0; i < 4; ++i) {
    float4 o = {acc[i][0], acc[i][1], acc[i][2], acc[i][3]};
    *(float4*)(wow + (size_t)(m0 + 4 * rq + i) * U + c0 + 4 * cq) = o;
  }
}

// -------- z0[u] = h0 @ w_y[:,u];  b_ow[u] = b_out @ w_y[:,u] --------
__global__ void k_vecs(const float* __restrict__ h0,
                       const float* __restrict__ b_out,
                       const float* __restrict__ w_y, float* __restrict__ z0,
                       float* __restrict__ b_ow) {
  const int u = (blockIdx.x & 3) * 256 + threadIdx.x;
  const int kb = blockIdx.x >> 2;  // 8 k-blocks x 128
  float a0 = 0.f, a1 = 0.f;
  for (int k = kb * 128; k < kb * 128 + 128; ++k) {
    float w = w_y[(size_t)k * U + u];
    a0 += h0[k] * w;
    a1 += b_out[k] * w;
  }
  atomicAdd(&z0[u], a0);
  atomicAdd(&b_ow[u], a1);
}

// -------- slot1[n][u] = h0_0 = lrelu(z0[u] + xp[0][n][u]) --------
__global__ void k_fill(const float* __restrict__ z0,
                       const float* __restrict__ xp,
                       float* __restrict__ slot1) {
  int i = blockIdx.x * 256 + threadIdx.x;  // grid 256 -> 65536
  float v = z0[i & (U - 1)] + xp[i];
  slot1[i] = LRELU(v);
}

// ---------------- sequential pipeline: 768 phases ----------------
// 256 WGs = 8 rg x 32 cg. Thread (s,ri,ci): K-slice [32s,32s+32), rows
// [4ri,4ri+4) of 8, cols [4ci,4ci+4) of 32. Partials -> red2 ([y|z], pitch
// 264 each). Phase Q = 3t+ph: ph0 A(w_h0), ph1 B(w_h1), ph2 C: FUSED loop
// (y-half from wreg=w_out, z-half inline w_ow) -> one barrier, one finalize.
__global__ __launch_bounds__(512) void k_seq(
    const float* __restrict__ xp, const float* __restrict__ w_h,
    const float* __restrict__ b_h, const float* __restrict__ w_out,
    const float* __restrict__ w_ow, const float* __restrict__ b_out,
    const float* __restrict__ b_ow, const float* __restrict__ z0,
    const float* __restrict__ h0, float* __restrict__ out,
    float* __restrict__ slots, unsigned* __restrict__ flags) {
  __shared__ float a_s[8 * APITCH];      // 9248 floats = 36992 B
  __shared__ float red2[2 * 32 * 264];   // 16896 floats = 67584 B
  const int tid = threadIdx.x;
  const int cg = blockIdx.x & 31, rg = blockIdx.x >> 5;
  const int l = tid & 63;
  const int ci = l & 7, ri = (l >> 3) & 1;
  const int s = (tid >> 6) * 4 + ((l >> 4) & 3);
  const int cb = 4 * ci, r0 = 4 * ri, k0 = 32 * s;
  unsigned* const myflag = &flags[rg * 32 + cg];
  const unsigned* const pollf = &flags[rg * 32 + (l & 31)];
  // finalize coordinates + loop-invariant operands (valid for all tid)
  const int frow = 8 * rg + (tid >> 5);
  const int fu = 32 * cg + (tid & 31);
  const size_t fyi = (size_t)frow * U + fu;
  const float bh0r = b_h[fu], bh1r = b_h[U + fu];
  const float bor = b_out[fu], bowr = b_ow[fu];
  float y_reg = h0[fu];  // y_0 = broadcast(h0)
  float z_reg = z0[fu];  // z_0 = broadcast(h0 @ w_y)
  // z-half W pointer (loop-invariant)
  const float* const wp2 = w_ow + (size_t)k0 * U + 32 * cg + cb;

  // W panel base for phase type 0/1/2 (wreg source)
  auto wbase = [&](int pht) -> const float* {
    const float* Wsrc = (pht == 0)   ? w_h
                        : (pht == 1) ? (w_h + (size_t)U * U)
                                     : w_out;
    return Wsrc + (size_t)k0 * U + 32 * cg + cb;
  };
  f4 wreg[32];
  {
    const float* wp = wbase(0);
#pragma unroll
    for (int j = 0; j < 32; ++j) wreg[j] = *(const f4*)(wp + (size_t)j * U);
  }

  int t = 0, ph = 0;
  for (int Q = 0; Q < 3 * T; ++Q) {
    const float* Asrc =
        slots + (size_t)((Q + 1) & 1) * BU + (size_t)(8 * rg) * U;
    float* slotw = slots + (size_t)(Q & 1) * BU;
    // ---- 0. xp prefetch for C (next timestep's xproj; hides under poll) ---
    float xpre = 0.f;
    if (ph == 2 && tid < 256) {
      const int tn = (t < T - 1) ? t + 1 : t;  // clamped; unused at t=T-1
      xpre = xp[((size_t)tn * B + frow) * U + fu];
    }
    // ---- 1. acquire: wave0's 32 lanes, one 128B flag read, bounded ----
    if (Q > 0) {
      if (tid < 64) {
        const unsigned tg = (unsigned)Q;
        for (int it = 0; it < (1 << 20); ++it) {
          unsigned f = llc_flag(pollf);
          if (__all((int)(f >= tg))) break;
          __builtin_amdgcn_s_sleep(1);
        }
      }
      __syncthreads();
      asm volatile("" ::: "memory");
    }
    // ---- 2. stage A: 8 rows x 1024, 8B sc1 loads -> b128 LDS write ----
#pragma unroll
    for (int rep = 0; rep < 4; ++rep) {
      int idx4 = 512 * rep + tid;
      int row = idx4 >> 8, kq = idx4 & 255, k = 4 * kq;
      const float* pa = Asrc + (size_t)row * U + k;
      unsigned long long v0 = llc_load64(pa);
      unsigned long long v1 = llc_load64(pa + 2);
      f4 v;
      ((unsigned long long*)&v)[0] = v0;
      ((unsigned long long*)&v)[1] = v1;
      *(f4*)&a_s[row * APITCH + 36 * (k >> 5) + (k & 31)] = v;
    }
    __syncthreads();
    // ---- 3. GEMM ----
    const int abase = r0 * APITCH + 36 * s;
    f4 acc[4];
#pragma unroll
    for (int i = 0; i < 4; ++i) acc[i] = (f4){0.f, 0.f, 0.f, 0.f};
    if (ph < 2) {
#pragma unroll
      for (int q = 0; q < 8; ++q) {
        const int ai = abase + 4 * q;
        f4 a0 = *(const f4*)&a_s[ai];
        f4 a1 = *(const f4*)&a_s[ai + APITCH];
        f4 a2 = *(const f4*)&a_s[ai + 2 * APITCH];
        f4 a3 = *(const f4*)&a_s[ai + 3 * APITCH];
        const f4 w0 = wreg[4 * q], w1 = wreg[4 * q + 1];
        const f4 w2 = wreg[4 * q + 2], w3 = wreg[4 * q + 3];
        acc[0] += a0.x * w0 + a0.y * w1 + a0.z * w2 + a0.w * w3;
        acc[1] += a1.x * w0 + a1.y * w1 + a1.z * w2 + a1.w * w3;
        acc[2] += a2.x * w0 + a2.y * w1 + a2.z * w2 + a2.w * w3;
        acc[3] += a3.x * w0 + a3.y * w1 + a3.z * w2 + a3.w * w3;
      }
#pragma unroll
      for (int i = 0; i < 4; ++i)
        *(f4*)&red2[s * 264 + (r0 + i) * 32 + cb] = acc[i];
      __syncthreads();
      if (tid < 256) {
        float sum = 0.f;
#pragma unroll
        for (int z = 0; z < 32; ++z) sum += red2[z * 264 + tid];
        float v = sum + (ph ? bh1r : bh0r);
        llc_store(slotw + fyi, LRELU(v));
      }
    } else {
      // C FUSED: y-half from wreg (w_out), z-half inline w_ow -- the wreg
      // FMA work hides the in-flight w_ow LLC loads (R17's exposed pass-2).
      f4 accz[4];
#pragma unroll
      for (int i = 0; i < 4; ++i) accz[i] = (f4){0.f, 0.f, 0.f, 0.f};
#pragma unroll
      for (int q = 0; q < 8; ++q) {
        const int ai = abase + 4 * q;
        f4 a0 = *(const f4*)&a_s[ai];
        f4 a1 = *(const f4*)&a_s[ai + APITCH];
        f4 a2 = *(const f4*)&a_s[ai + 2 * APITCH];
        f4 a3 = *(const f4*)&a_s[ai + 3 * APITCH];
        const f4 w0 = wreg[4 * q], w1 = wreg[4 * q + 1];
        const f4 w2 = wreg[4 * q + 2], w3 = wreg[4 * q + 3];
        acc[0] += a0.x * w0 + a0.y * w1 + a0.z * w2 + a0.w * w3;
        acc[1] += a1.x * w0 + a1.y * w1 + a1.z * w2 + a1.w * w3;
        acc[2] += a2.x * w0 + a2.y * w1 + a2.z * w2 + a2.w * w3;
        acc[3] += a3.x * w0 + a3.y * w1 + a3.z * w2 + a3.w * w3;
        const f4 v0 = *(const f4*)(wp2 + (size_t)(4 * q) * U);
        const f4 v1 = *(const f4*)(wp2 + (size_t)(4 * q + 1) * U);
        const f4 v2 = *(const f4*)(wp2 + (size_t)(4 * q + 2) * U);
        const f4 v3 = *(const f4*)(wp2 + (size_t)(4 * q + 3) * U);
        accz[0] += a0.x * v0 + a0.y * v1 + a0.z * v2 + a0.w * v3;
        accz[1] += a1.x * v0 + a1.y * v1 + a1.z * v2 + a1.w * v3;
        accz[2] += a2.x * v0 + a2.y * v1 + a2.z * v2 + a2.w * v3;
        accz[3] += a3.x * v0 + a3.y * v1 + a3.z * v2 + a3.w * v3;
      }
#pragma unroll
      for (int i = 0; i < 4; ++i) {
        *(f4*)&red2[s * 264 + (r0 + i) * 32 + cb] = acc[i];
        *(f4*)&red2[RZOFF + s * 264 + (r0 + i) * 32 + cb] = accz[i];
      }
      __syncthreads();
      if (tid < 256) {
        float ysum = 0.f, zsum = 0.f;
#pragma unroll
        for (int z = 0; z < 32; ++z) {
          ysum += red2[z * 264 + tid];
          zsum += red2[RZOFF + z * 264 + tid];
        }
        y_reg += ysum + bor;  // out-store deferred past flag post
        z_reg += zsum + bowr;
        if (t < T - 1) {  // h0' for the next timestep's phase A
          float v = z_reg + xpre;
          llc_store(slotw + fyi, LRELU(v));
        }
      }
    }
    // ---- 6. drain: exchange stores at LLC before the flag post ----
    asm volatile("" ::: "memory");
    __builtin_amdgcn_s_waitcnt(0);
    __syncthreads();
    // ---- 7. W prefetch for Q+1 (SINGLE reload site; overlaps post + poll
    //         + next stage -- R13's proven pattern) ----
    if (Q < 3 * T - 1) {
      const float* wp = wbase(ph == 2 ? 0 : ph + 1);
#pragma unroll
      for (int j = 0; j < 32; ++j) wreg[j] = *(const f4*)(wp + (size_t)j * U);
    }
    // ---- 8. release: per-producer flag store ----
    if (tid == 0) llc_flag_store(myflag, (unsigned)(Q + 1));
    // ---- 9. deferred out-store (off the flag critical path) ----
    if (ph == 2 && tid < 256) out[((size_t)frow * T + t) * U + fu] = y_reg;
    if (++ph == 3) {
      ph = 0;
      ++t;
    }
  }
}

extern "C" void kernel_launch(void* const* d_in, const int* in_sizes, int n_in,
                              void* d_out, int out_size, void* d_ws,
                              size_t ws_size, hipStream_t stream) {
  const int* x = (const int*)d_in[0];
  const float* emb = (const float*)d_in[1];
  const float* w_y = (const float*)d_in[2];
  const float* w_x = (const float*)d_in[3];
  const float* b_in = (const float*)d_in[4];
  const float* w_h = (const float*)d_in[5];
  const float* b_h = (const float*)d_in[6];
  const float* w_out = (const float*)d_in[7];
  const float* b_out = (const float*)d_in[8];
  const float* h0 = (const float*)d_in[9];
  float* out = (float*)d_out;

  // workspace (floats): xproj | slots[2] | flags(1024u) | z0 | b_ow | w_ow
  float* ws = (float*)d_ws;
  float* xpb = ws;                         // T*B*U = 16,777,216
  float* slots = xpb + (size_t)T * B * U;  // 2*BU = 131,072
  unsigned* flags = (unsigned*)(slots + 2 * (size_t)BU);  // 1024 uints
  float* z0 = (float*)(flags + 1024);      // 1024
  float* b_ow = z0 + 1024;                 // 1024
  float* w_ow = b_ow + 1024;               // U*U = 1,048,576 (4 MB)

  k_init<<<4, 256, 0, stream>>>(flags, z0, b_ow);
  dim3 g1(256, 16);
  k_xproj<<<g1, 256, 0, stream>>>(x, emb, w_x, b_in, xpb);
  dim3 g2(16, 16);
  k_wcat<<<g2, 256, 0, stream>>>(w_out, w_y, w_ow);
  k_vecs<<<32, 256, 0, stream>>>(h0, b_out, w_y, z0, b_ow);
  k_fill<<<256, 256, 0, stream>>>(z0, xpb, slots + (size_t)BU);

  void* args[] = {&xpb,  &w_h, &b_h, &w_out, &w_ow,  &b_out,
                  &b_ow, &z0,  &h0,  &out,   &slots, &flags};
  hipLaunchCooperativeKernel((void*)k_seq, dim3(256), dim3(512), args, 0u,
                             stream);
}

// Round 12
// 7801.666 us; speedup vs baseline: 1.0425x; 1.0425x over previous
//
#include <hip/hip_runtime.h>

// HighwayLayerDiscrete: 256-step recurrent highway net, batch 64, units 1024.
// Reference per step: p0 h=lrelu(y@w_y+xe@w_x+b_in); p1/p2 h=lrelu(h@w_h+b_h);
// p3 y += h@w_out + b_out; out[:,t,:]=y.
//
// R19 = R18 (8.13 ms, 3-phase refold + fused C) + w_ow L2 WARMING.
// R17/R18 post-mortem: phase C is slow (15-20us vs 6.1) because w_ow's 4MB
// is only touched in C -> L2-cold exactly when needed; its fill on the
// critical path evicts the other panels (R18 FETCH 6.7e6 KB > full-miss
// bound for w_ow alone = eviction cascade). R13's wh panels show ~75%
// L2-hit because they recur every 3rd phase. Fix: ONE scalar warming load
// per thread in phases A and B (row tid / tid+512, col 32cg = exactly the
// 1024 lines C reads per WG), issued after the stage barrier (not before:
// the pre-barrier waitcnt would expose it), kept alive by asm(:: "v")
// (rule 17), absorbed by the drain's waitcnt0. A/B have ~4.5us of
// memory-pipe idle to hide the fill; C then hits L2 (~200cy pipelined).
// Algebra (validated R14/R16/R17/R18): z_t := y_t @ w_y private state;
//   z' = z + h2@w_ow + b_ow (w_ow = w_out@w_y, b_ow = b_out@w_y, prologue);
//   h0' = lrelu(z' + xp[t+1]) elementwise-private; y' = y + h2@w_out + b_out
//   with y = 1 reg/thread, never staged. 3 exchanges/step (was 4).
// Carried R13 wins: per-producer flag stores + coalesced 32-lane poll
// (bounded); finalize operands prefetched; out-store deferred past flag post.
// Carried invariants: 256 coop blocks x 512 thr (R4); no cross-WG split-K
// (R2/R3); no fences (R1); sc1/LLC only (R9: sc0 deadlocks); release =
// waitcnt0+barrier+flag store; acquire = poll+barrier+clobber; LDS skew
// injective (R5); red2 de-aliased; SINGLE wreg reload site (R16: a second
// site forces wreg live-doubling -> 113GB scratch spill).

constexpr int B = 64, T = 256, U = 1024, E = 512;
constexpr int BU = B * U;     // 65536
constexpr int APITCH = 1156;  // A-row pitch (1024 + 36-skew; ==4 mod 8)
constexpr int RZOFF = 8448;   // red2 z-partials offset (32*264)

#define LRELU(v) ((v) > 0.f ? (v) : 0.2f * (v))

using f4 = float __attribute__((ext_vector_type(4)));

__device__ __forceinline__ unsigned long long llc_load64(const float* p) {
  return __hip_atomic_load((const unsigned long long*)p, __ATOMIC_RELAXED,
                           __HIP_MEMORY_SCOPE_AGENT);
}
__device__ __forceinline__ void llc_store(float* p, float v) {
  __hip_atomic_store(p, v, __ATOMIC_RELAXED, __HIP_MEMORY_SCOPE_AGENT);
}
__device__ __forceinline__ unsigned llc_flag(const unsigned* p) {
  return __hip_atomic_load(p, __ATOMIC_RELAXED, __HIP_MEMORY_SCOPE_AGENT);
}
__device__ __forceinline__ void llc_flag_store(unsigned* p, unsigned v) {
  __hip_atomic_store(p, v, __ATOMIC_RELAXED, __HIP_MEMORY_SCOPE_AGENT);
}

// -------- init: zero flags and the k_vecs atomic accumulators --------
__global__ void k_init(unsigned* __restrict__ flags, float* __restrict__ z0,
                       float* __restrict__ b_ow) {
  int i = blockIdx.x * 256 + threadIdx.x;  // grid 4 -> 1024
  if (i < 1024) {
    flags[i] = 0u;
    z0[i] = 0.f;
    b_ow[i] = 0.f;
  }
}

// ------- xproj[t*64+n][u] = emb[x[n][t]] @ w_x + b_in (R2/R3-proven) -------
__global__ __launch_bounds__(256) void k_xproj(
    const int* __restrict__ x, const float* __restrict__ emb,
    const float* __restrict__ w_x, const float* __restrict__ b_in,
    float* __restrict__ xp) {
  __shared__ float a_s[64][36];
  __shared__ float w_s[32][64];
  __shared__ int idxs[64];
  const int tid = threadIdx.x;
  const int m0 = blockIdx.x * 64;
  const int c0 = blockIdx.y * 64;
  if (tid < 64) {
    int m = m0 + tid;
    idxs[tid] = x[(m & 63) * T + (m >> 6)];  // x[n][t], row m = t*64+n
  }
  __syncthreads();
  const int rq = tid >> 4, cq = tid & 15;
  float acc[4][4] = {};
  for (int k0 = 0; k0 < E; k0 += 32) {
#pragma unroll
    for (int rep = 0; rep < 8; ++rep) {
      int e = rep * 256 + tid;
      int r = e >> 5, k = e & 31;
      a_s[r][k] = emb[(size_t)idxs[r] * E + k0 + k];
    }
#pragma unroll
    for (int rep = 0; rep < 2; ++rep) {
      int e = rep * 256 + tid;
      int kr = e >> 4, q = e & 15;
      *(float4*)&w_s[kr][4 * q] =
          *(const float4*)(w_x + (size_t)(k0 + kr) * U + c0 + 4 * q);
    }
    __syncthreads();
#pragma unroll
    for (int kc = 0; kc < 32; kc += 4) {
      float4 a4[4], w4[4];
#pragma unroll
      for (int i = 0; i < 4; ++i) a4[i] = *(const float4*)&a_s[4 * rq + i][kc];
#pragma unroll
      for (int kk = 0; kk < 4; ++kk)
        w4[kk] = *(const float4*)&w_s[kc + kk][4 * cq];
#pragma unroll
      for (int i = 0; i < 4; ++i) {
        const float av[4] = {a4[i].x, a4[i].y, a4[i].z, a4[i].w};
#pragma unroll
        for (int kk = 0; kk < 4; ++kk) {
          acc[i][0] += av[kk] * w4[kk].x;
          acc[i][1] += av[kk] * w4[kk].y;
          acc[i][2] += av[kk] * w4[kk].z;
          acc[i][3] += av[kk] * w4[kk].w;
        }
      }
    }
    __syncthreads();
  }
  const float4 bb = *(const float4*)(b_in + c0 + 4 * cq);
  const float bv[4] = {bb.x, bb.y, bb.z, bb.w};
#pragma unroll
  for (int i = 0; i < 4; ++i) {
    float4 o;
    o.x = acc[i][0] + bv[0];
    o.y = acc[i][1] + bv[1];
    o.z = acc[i][2] + bv[2];
    o.w = acc[i][3] + bv[3];
    *(float4*)(xp + (size_t)(m0 + 4 * rq + i) * U + c0 + 4 * cq) = o;
  }
}

// -------- w_ow[k][u] = sum_j w_out[k][j] * w_y[j][u]  (same tile GEMM) -----
__global__ __launch_bounds__(256) void k_wcat(const float* __restrict__ wo,
                                              const float* __restrict__ wy,
                                              float* __restrict__ wow) {
  __shared__ float a_s[64][36];
  __shared__ float w_s[32][64];
  const int tid = threadIdx.x;
  const int m0 = blockIdx.x * 64;
  const int c0 = blockIdx.y * 64;
  const int rq = tid >> 4, cq = tid & 15;
  float acc[4][4] = {};
  for (int k0 = 0; k0 < U; k0 += 32) {
#pragma unroll
    for (int rep = 0; rep < 8; ++rep) {
      int e = rep * 256 + tid;
      int r = e >> 5, k = e & 31;
      a_s[r][k] = wo[(size_t)(m0 + r) * U + k0 + k];
    }
#pragma unroll
    for (int rep = 0; rep < 2; ++rep) {
      int e = rep * 256 + tid;
      int kr = e >> 4, q = e & 15;
      *(float4*)&w_s[kr][4 * q] =
          *(const float4*)(wy + (size_t)(k0 + kr) * U + c0 + 4 * q);
    }
    __syncthreads();
#pragma unroll
    for (int kc = 0; kc < 32; kc += 4) {
      float4 a4[4], w4[4];
#pragma unroll
      for (int i = 0; i < 4; ++i) a4[i] = *(const float4*)&a_s[4 * rq + i][kc];
#pragma unroll
      for (int kk = 0; kk < 4; ++kk)
        w4[kk] = *(const float4*)&w_s[kc + kk][4 * cq];
#pragma unroll
      for (int i = 0; i < 4; ++i) {
        const float av[4] = {a4[i].x, a4[i].y, a4[i].z, a4[i].w};
#pragma unroll
        for (int kk = 0; kk < 4; ++kk) {
          acc[i][0] += av[kk] * w4[kk].x;
          acc[i][1] += av[kk] * w4[kk].y;
          acc[i][2] += av[kk] * w4[kk].z;
          acc[i][3] += av[kk] * w4[kk].w;
        }
      }
    }
    __syncthreads();
  }
#pragma unroll
  for (int i = 0; i < 4; ++i) {
    float4 o = {acc[i][0], acc[i][1], acc[i][2], acc[i][3]};
    *(float4*)(wow + (size_t)(m0 + 4 * rq + i) * U + c0 + 4 * cq) = o;
  }
}

// -------- z0[u] = h0 @ w_y[:,u];  b_ow[u] = b_out @ w_y[:,u] --------
__global__ void k_vecs(const float* __restrict__ h0,
                       const float* __restrict__ b_out,
                       const float* __restrict__ w_y, float* __restrict__ z0,
                       float* __restrict__ b_ow) {
  const int u = (blockIdx.x & 3) * 256 + threadIdx.x;
  const int kb = blockIdx.x >> 2;  // 8 k-blocks x 128
  float a0 = 0.f, a1 = 0.f;
  for (int k = kb * 128; k < kb * 128 + 128; ++k) {
    float w = w_y[(size_t)k * U + u];
    a0 += h0[k] * w;
    a1 += b_out[k] * w;
  }
  atomicAdd(&z0[u], a0);
  atomicAdd(&b_ow[u], a1);
}

// -------- slot1[n][u] = h0_0 = lrelu(z0[u] + xp[0][n][u]) --------
__global__ void k_fill(const float* __restrict__ z0,
                       const float* __restrict__ xp,
                       float* __restrict__ slot1) {
  int i = blockIdx.x * 256 + threadIdx.x;  // grid 256 -> 65536
  float v = z0[i & (U - 1)] + xp[i];
  slot1[i] = LRELU(v);
}

// ---------------- sequential pipeline: 768 phases ----------------
// 256 WGs = 8 rg x 32 cg. Thread (s,ri,ci): K-slice [32s,32s+32), rows
// [4ri,4ri+4) of 8, cols [4ci,4ci+4) of 32. Partials -> red2 ([y|z], pitch
// 264 each). Phase Q = 3t+ph: ph0 A(w_h0)+warm(w_ow lo), ph1 B(w_h1)+warm
// (w_ow hi), ph2 C fused (y from wreg=w_out, z inline w_ow -- L2-warm).
__global__ __launch_bounds__(512) void k_seq(
    const float* __restrict__ xp, const float* __restrict__ w_h,
    const float* __restrict__ b_h, const float* __restrict__ w_out,
    const float* __restrict__ w_ow, const float* __restrict__ b_out,
    const float* __restrict__ b_ow, const float* __restrict__ z0,
    const float* __restrict__ h0, float* __restrict__ out,
    float* __restrict__ slots, unsigned* __restrict__ flags) {
  __shared__ float a_s[8 * APITCH];     // 9248 floats = 36992 B
  __shared__ float red2[2 * 32 * 264];  // 16896 floats = 67584 B
  const int tid = threadIdx.x;
  const int cg = blockIdx.x & 31, rg = blockIdx.x >> 5;
  const int l = tid & 63;
  const int ci = l & 7, ri = (l >> 3) & 1;
  const int s = (tid >> 6) * 4 + ((l >> 4) & 3);
  const int cb = 4 * ci, r0 = 4 * ri, k0 = 32 * s;
  unsigned* const myflag = &flags[rg * 32 + cg];
  const unsigned* const pollf = &flags[rg * 32 + (l & 31)];
  // finalize coordinates + loop-invariant operands (valid for all tid)
  const int frow = 8 * rg + (tid >> 5);
  const int fu = 32 * cg + (tid & 31);
  const size_t fyi = (size_t)frow * U + fu;
  const float bh0r = b_h[fu], bh1r = b_h[U + fu];
  const float bor = b_out[fu], bowr = b_ow[fu];
  float y_reg = h0[fu];  // y_0 = broadcast(h0)
  float z_reg = z0[fu];  // z_0 = broadcast(h0 @ w_y)
  // z-half W pointer (loop-invariant); warming address base (line-exact:
  // the WG's C reads of row k are cols 32cg..32cg+31 = one 128B line)
  const float* const wp2 = w_ow + (size_t)k0 * U + 32 * cg + cb;
  const float* const wwarm = w_ow + 32 * cg;

  // W panel base for phase type 0/1/2 (wreg source)
  auto wbase = [&](int pht) -> const float* {
    const float* Wsrc = (pht == 0)   ? w_h
                        : (pht == 1) ? (w_h + (size_t)U * U)
                                     : w_out;
    return Wsrc + (size_t)k0 * U + 32 * cg + cb;
  };
  f4 wreg[32];
  {
    const float* wp = wbase(0);
#pragma unroll
    for (int j = 0; j < 32; ++j) wreg[j] = *(const f4*)(wp + (size_t)j * U);
  }

  int t = 0, ph = 0;
  for (int Q = 0; Q < 3 * T; ++Q) {
    const float* Asrc =
        slots + (size_t)((Q + 1) & 1) * BU + (size_t)(8 * rg) * U;
    float* slotw = slots + (size_t)(Q & 1) * BU;
    // ---- 0. xp prefetch for C (next timestep's xproj; hides under poll) ---
    float xpre = 0.f;
    if (ph == 2 && tid < 256) {
      const int tn = (t < T - 1) ? t + 1 : t;  // clamped; unused at t=T-1
      xpre = xp[((size_t)tn * B + frow) * U + fu];
    }
    // ---- 1. acquire: wave0's 32 lanes, one 128B flag read, bounded ----
    if (Q > 0) {
      if (tid < 64) {
        const unsigned tg = (unsigned)Q;
        for (int it = 0; it < (1 << 20); ++it) {
          unsigned f = llc_flag(pollf);
          if (__all((int)(f >= tg))) break;
          __builtin_amdgcn_s_sleep(1);
        }
      }
      __syncthreads();
      asm volatile("" ::: "memory");
    }
    // ---- 2. stage A: 8 rows x 1024, 8B sc1 loads -> b128 LDS write ----
#pragma unroll
    for (int rep = 0; rep < 4; ++rep) {
      int idx4 = 512 * rep + tid;
      int row = idx4 >> 8, kq = idx4 & 255, k = 4 * kq;
      const float* pa = Asrc + (size_t)row * U + k;
      unsigned long long v0 = llc_load64(pa);
      unsigned long long v1 = llc_load64(pa + 2);
      f4 v;
      ((unsigned long long*)&v)[0] = v0;
      ((unsigned long long*)&v)[1] = v1;
      *(f4*)&a_s[row * APITCH + 36 * (k >> 5) + (k & 31)] = v;
    }
    __syncthreads();
    // ---- 2b. w_ow L2 warming (A: rows 0..511, B: rows 512..1023); issued
    //          AFTER the barrier so the stage waitcnt doesn't expose it;
    //          consumed only by the keep-alive asm before the drain ----
    float warm = 0.f;
    if (ph == 0) warm = wwarm[(size_t)tid * U];
    else if (ph == 1) warm = wwarm[(size_t)(tid + 512) * U];
    // ---- 3. GEMM ----
    const int abase = r0 * APITCH + 36 * s;
    f4 acc[4];
#pragma unroll
    for (int i = 0; i < 4; ++i) acc[i] = (f4){0.f, 0.f, 0.f, 0.f};
    if (ph < 2) {
#pragma unroll
      for (int q = 0; q < 8; ++q) {
        const int ai = abase + 4 * q;
        f4 a0 = *(const f4*)&a_s[ai];
        f4 a1 = *(const f4*)&a_s[ai + APITCH];
        f4 a2 = *(const f4*)&a_s[ai + 2 * APITCH];
        f4 a3 = *(const f4*)&a_s[ai + 3 * APITCH];
        const f4 w0 = wreg[4 * q], w1 = wreg[4 * q + 1];
        const f4 w2 = wreg[4 * q + 2], w3 = wreg[4 * q + 3];
        acc[0] += a0.x * w0 + a0.y * w1 + a0.z * w2 + a0.w * w3;
        acc[1] += a1.x * w0 + a1.y * w1 + a1.z * w2 + a1.w * w3;
        acc[2] += a2.x * w0 + a2.y * w1 + a2.z * w2 + a2.w * w3;
        acc[3] += a3.x * w0 + a3.y * w1 + a3.z * w2 + a3.w * w3;
      }
#pragma unroll
      for (int i = 0; i < 4; ++i)
        *(f4*)&red2[s * 264 + (r0 + i) * 32 + cb] = acc[i];
      __syncthreads();
      if (tid < 256) {
        float sum = 0.f;
#pragma unroll
        for (int z = 0; z < 32; ++z) sum += red2[z * 264 + tid];
        float v = sum + (ph ? bh1r : bh0r);
        llc_store(slotw + fyi, LRELU(v));
      }
    } else {
      // C FUSED: y-half from wreg (w_out), z-half inline w_ow (L2-warm).
      f4 accz[4];
#pragma unroll
      for (int i = 0; i < 4; ++i) accz[i] = (f4){0.f, 0.f, 0.f, 0.f};
#pragma unroll
      for (int q = 0; q < 8; ++q) {
        const int ai = abase + 4 * q;
        f4 a0 = *(const f4*)&a_s[ai];
        f4 a1 = *(const f4*)&a_s[ai + APITCH];
        f4 a2 = *(const f4*)&a_s[ai + 2 * APITCH];
        f4 a3 = *(const f4*)&a_s[ai + 3 * APITCH];
        const f4 w0 = wreg[4 * q], w1 = wreg[4 * q + 1];
        const f4 w2 = wreg[4 * q + 2], w3 = wreg[4 * q + 3];
        acc[0] += a0.x * w0 + a0.y * w1 + a0.z * w2 + a0.w * w3;
        acc[1] += a1.x * w0 + a1.y * w1 + a1.z * w2 + a1.w * w3;
        acc[2] += a2.x * w0 + a2.y * w1 + a2.z * w2 + a2.w * w3;
        acc[3] += a3.x * w0 + a3.y * w1 + a3.z * w2 + a3.w * w3;
        const f4 v0 = *(const f4*)(wp2 + (size_t)(4 * q) * U);
        const f4 v1 = *(const f4*)(wp2 + (size_t)(4 * q + 1) * U);
        const f4 v2 = *(const f4*)(wp2 + (size_t)(4 * q + 2) * U);
        const f4 v3 = *(const f4*)(wp2 + (size_t)(4 * q + 3) * U);
        accz[0] += a0.x * v0 + a0.y * v1 + a0.z * v2 + a0.w * v3;
        accz[1] += a1.x * v0 + a1.y * v1 + a1.z * v2 + a1.w * v3;
        accz[2] += a2.x * v0 + a2.y * v1 + a2.z * v2 + a2.w * v3;
        accz[3] += a3.x * v0 + a3.y * v1 + a3.z * v2 + a3.w * v3;
      }
#pragma unroll
      for (int i = 0; i < 4; ++i) {
        *(f4*)&red2[s * 264 + (r0 + i) * 32 + cb] = acc[i];
        *(f4*)&red2[RZOFF + s * 264 + (r0 + i) * 32 + cb] = accz[i];
      }
      __syncthreads();
      if (tid < 256) {
        float ysum = 0.f, zsum = 0.f;
#pragma unroll
        for (int z = 0; z < 32; ++z) {
          ysum += red2[z * 264 + tid];
          zsum += red2[RZOFF + z * 264 + tid];
        }
        y_reg += ysum + bor;  // out-store deferred past flag post
        z_reg += zsum + bowr;
        if (t < T - 1) {  // h0' for the next timestep's phase A
          float v = z_reg + xpre;
          llc_store(slotw + fyi, LRELU(v));
        }
      }
    }
    // ---- 5b. keep warming load alive (no numeric effect); its completion
    //          is absorbed by the drain's waitcnt0 ----
    asm volatile("" ::"v"(warm));
    // ---- 6. drain: exchange stores at LLC before the flag post ----
    asm volatile("" ::: "memory");
    __builtin_amdgcn_s_waitcnt(0);
    __syncthreads();
    // ---- 7. W prefetch for Q+1 (SINGLE reload site; overlaps post + poll
    //         + next stage -- R13's proven pattern) ----
    if (Q < 3 * T - 1) {
      const float* wp = wbase(ph == 2 ? 0 : ph + 1);
#pragma unroll
      for (int j = 0; j < 32; ++j) wreg[j] = *(const f4*)(wp + (size_t)j * U);
    }
    // ---- 8. release: per-producer flag store ----
    if (tid == 0) llc_flag_store(myflag, (unsigned)(Q + 1));
    // ---- 9. deferred out-store (off the flag critical path) ----
    if (ph == 2 && tid < 256) out[((size_t)frow * T + t) * U + fu] = y_reg;
    if (++ph == 3) {
      ph = 0;
      ++t;
    }
  }
}

extern "C" void kernel_launch(void* const* d_in, const int* in_sizes, int n_in,
                              void* d_out, int out_size, void* d_ws,
                              size_t ws_size, hipStream_t stream) {
  const int* x = (const int*)d_in[0];
  const float* emb = (const float*)d_in[1];
  const float* w_y = (const float*)d_in[2];
  const float* w_x = (const float*)d_in[3];
  const float* b_in = (const float*)d_in[4];
  const float* w_h = (const float*)d_in[5];
  const float* b_h = (const float*)d_in[6];
  const float* w_out = (const float*)d_in[7];
  const float* b_out = (const float*)d_in[8];
  const float* h0 = (const float*)d_in[9];
  float* out = (float*)d_out;

  // workspace (floats): xproj | slots[2] | flags(1024u) | z0 | b_ow | w_ow
  float* ws = (float*)d_ws;
  float* xpb = ws;                         // T*B*U = 16,777,216
  float* slots = xpb + (size_t)T * B * U;  // 2*BU = 131,072
  unsigned* flags = (unsigned*)(slots + 2 * (size_t)BU);  // 1024 uints
  float* z0 = (float*)(flags + 1024);      // 1024
  float* b_ow = z0 + 1024;                 // 1024
  float* w_ow = b_ow + 1024;               // U*U = 1,048,576 (4 MB)

  k_init<<<4, 256, 0, stream>>>(flags, z0, b_ow);
  dim3 g1(256, 16);
  k_xproj<<<g1, 256, 0, stream>>>(x, emb, w_x, b_in, xpb);
  dim3 g2(16, 16);
  k_wcat<<<g2, 256, 0, stream>>>(w_out, w_y, w_ow);
  k_vecs<<<32, 256, 0, stream>>>(h0, b_out, w_y, z0, b_ow);
  k_fill<<<256, 256, 0, stream>>>(z0, xpb, slots + (size_t)BU);

  void* args[] = {&xpb,  &w_h, &b_h, &w_out, &w_ow,  &b_out,
                  &b_ow, &z0,  &h0,  &out,   &slots, &flags};
  hipLaunchCooperativeKernel((void*)k_seq, dim3(256), dim3(512), args, 0u,
                             stream);
}

// Round 13
// 6184.953 us; speedup vs baseline: 1.3150x; 1.2614x over previous
//
#include <hip/hip_runtime.h>

// HighwayLayerDiscrete: 256-step recurrent highway net, batch 64, units 1024.
// Phase P = t*4+p: p0: h=lrelu(y@w_y + xproj[t]); p1/p2: h=lrelu(h@w_h[l]+b_h[l]);
// p3: y += h@w_out + b_out; out[:,t,:]=y.
//
// R20 = R13 (proven best, 6.23 ms) + two residual local edits. The R14-R19
// z-state refold (3 exchanges/step) is DEAD: its w_ow panel pushes the
// per-XCD working set past the 4MB L2 cliff (FETCH 1.1e6 -> 6.8e6 KB;
// warming moved no misses). The 4-phase working set is what fits L2.
//  1. red2 DE-ALIASED from a_s (70.8 KB LDS total, 1 WG/CU): removes the
//     compute->red2 alias-ordering barrier. Barriers/phase 5 -> 4. (Prev
//     finalize reads are sealed by the drain barrier; red2 writes only need
//     to precede B1.) This piece was correct in R8; its regression there
//     came from the confounded per-wave poll + scattered staging.
//  2. BIAS HOIST: b_h[fu], b_h[U+fu], b_out[fu] loaded once into registers
//     (R13 reloaded b_h from global inside finalize every p1/p2 phase, on
//     the release critical path).
// Carried R13 wins: per-producer flag STORES (no 32-way RMW on one LLC
// line) + coalesced 32-lane poll (bounded 2^20); xpre/ypre finalize-operand
// prefetch at phase start; p3 out-store deferred past the flag post.
// Carried invariants: 256 coop blocks x 512 thr (R4: >256 silently fails);
// no cross-WG split-K (R2/R3); no fences ever (R1: wbl2/inv = 66 ms);
// cross-WG data via relaxed agent-scope atomics (sc1 at LLC); release =
// waitcnt0+barrier+flag store; acquire = poll + barrier + asm clobber;
// LDS skew injective (R5); single wreg reload site (R16: two sites ->
// live-doubling -> 113GB scratch spill); no restructures of the R7 phase
// body (R8/R11/R12 all regressed it).

constexpr int B = 64, T = 256, U = 1024, E = 512;
constexpr int BU = B * U;     // 65536
constexpr int APITCH = 1156;  // A-row pitch (1024 + 36-skew; ==4 mod 8)
constexpr int RPITCH = 264;   // red2 per-s pitch

#define LRELU(v) ((v) > 0.f ? (v) : 0.2f * (v))

using f4 = float __attribute__((ext_vector_type(4)));

__device__ __forceinline__ unsigned long long llc_load64(const float* p) {
  return __hip_atomic_load((const unsigned long long*)p, __ATOMIC_RELAXED,
                           __HIP_MEMORY_SCOPE_AGENT);
}
__device__ __forceinline__ void llc_store(float* p, float v) {
  __hip_atomic_store(p, v, __ATOMIC_RELAXED, __HIP_MEMORY_SCOPE_AGENT);
}
__device__ __forceinline__ unsigned llc_flag(const unsigned* p) {
  return __hip_atomic_load(p, __ATOMIC_RELAXED, __HIP_MEMORY_SCOPE_AGENT);
}
__device__ __forceinline__ void llc_flag_store(unsigned* p, unsigned v) {
  __hip_atomic_store(p, v, __ATOMIC_RELAXED, __HIP_MEMORY_SCOPE_AGENT);
}

// ---------------- init: zero flags, y0 into slot1 and ybuf ----------------
__global__ void k_init(float* __restrict__ slot1, float* __restrict__ ybuf,
                       const float* __restrict__ h0,
                       unsigned* __restrict__ flags) {
  int tid = blockIdx.x * 256 + threadIdx.x;
  if (tid < 512) flags[tid] = 0u;
  if (tid < BU) {
    float v = h0[tid & (U - 1)];
    slot1[tid] = v;
    ybuf[tid] = v;
  }
}

// ------- xproj[t*64+n][u] = emb[x[n][t]] @ w_x + b_in (R2/R3-proven) -------
__global__ __launch_bounds__(256) void k_xproj(
    const int* __restrict__ x, const float* __restrict__ emb,
    const float* __restrict__ w_x, const float* __restrict__ b_in,
    float* __restrict__ xp) {
  __shared__ float a_s[64][36];
  __shared__ float w_s[32][64];
  __shared__ int idxs[64];
  const int tid = threadIdx.x;
  const int m0 = blockIdx.x * 64;
  const int c0 = blockIdx.y * 64;
  if (tid < 64) {
    int m = m0 + tid;
    idxs[tid] = x[(m & 63) * T + (m >> 6)];  // x[n][t], row m = t*64+n
  }
  __syncthreads();
  const int rq = tid >> 4, cq = tid & 15;
  float acc[4][4] = {};
  for (int k0 = 0; k0 < E; k0 += 32) {
#pragma unroll
    for (int rep = 0; rep < 8; ++rep) {
      int e = rep * 256 + tid;
      int r = e >> 5, k = e & 31;
      a_s[r][k] = emb[(size_t)idxs[r] * E + k0 + k];
    }
#pragma unroll
    for (int rep = 0; rep < 2; ++rep) {
      int e = rep * 256 + tid;
      int kr = e >> 4, q = e & 15;
      *(float4*)&w_s[kr][4 * q] =
          *(const float4*)(w_x + (size_t)(k0 + kr) * U + c0 + 4 * q);
    }
    __syncthreads();
#pragma unroll
    for (int kc = 0; kc < 32; kc += 4) {
      float4 a4[4], w4[4];
#pragma unroll
      for (int i = 0; i < 4; ++i) a4[i] = *(const float4*)&a_s[4 * rq + i][kc];
#pragma unroll
      for (int kk = 0; kk < 4; ++kk)
        w4[kk] = *(const float4*)&w_s[kc + kk][4 * cq];
#pragma unroll
      for (int i = 0; i < 4; ++i) {
        const float av[4] = {a4[i].x, a4[i].y, a4[i].z, a4[i].w};
#pragma unroll
        for (int kk = 0; kk < 4; ++kk) {
          acc[i][0] += av[kk] * w4[kk].x;
          acc[i][1] += av[kk] * w4[kk].y;
          acc[i][2] += av[kk] * w4[kk].z;
          acc[i][3] += av[kk] * w4[kk].w;
        }
      }
    }
    __syncthreads();
  }
  const float4 bb = *(const float4*)(b_in + c0 + 4 * cq);
  const float bv[4] = {bb.x, bb.y, bb.z, bb.w};
#pragma unroll
  for (int i = 0; i < 4; ++i) {
    float4 o;
    o.x = acc[i][0] + bv[0];
    o.y = acc[i][1] + bv[1];
    o.z = acc[i][2] + bv[2];
    o.w = acc[i][3] + bv[3];
    *(float4*)(xp + (size_t)(m0 + 4 * rq + i) * U + c0 + 4 * cq) = o;
  }
}

// ---------------- sequential pipeline ----------------
// 256 WGs = 8 rg x 32 cg (XCD = cg&7, L2-affine). Thread (s,ri,ci): K-slice
// [32s,32s+32), rows [4ri,4ri+4) of 8, cols [4ci,4ci+4) of 32. Partials ->
// red2[s][out] pitch 264 (SEPARATE buffer). Barriers/phase: poll, stage,
// B1 (red2 ready), drain.
__global__ __launch_bounds__(512, 2) void k_seq(
    const float* __restrict__ xp, const float* __restrict__ w_y,
    const float* __restrict__ w_h, const float* __restrict__ b_h,
    const float* __restrict__ w_out, const float* __restrict__ b_out,
    float* __restrict__ out, float* __restrict__ slots,
    float* __restrict__ ybuf, unsigned* __restrict__ flags) {
  __shared__ float a_s[8 * APITCH];    // 9248 floats = 36992 B
  __shared__ float red2[32 * RPITCH];  // 8448 floats = 33792 B (de-aliased)
  const int tid = threadIdx.x;
  const int cg = blockIdx.x & 31, rg = blockIdx.x >> 5;
  const int l = tid & 63;
  const int ci = l & 7, ri = (l >> 3) & 1;
  const int s = (tid >> 6) * 4 + ((l >> 4) & 3);
  const int cb = 4 * ci, r0 = 4 * ri, k0 = 32 * s;
  unsigned* const myflag = &flags[rg * 32 + cg];
  const unsigned* const pollf = &flags[rg * 32 + (l & 31)];
  // finalize coordinates + hoisted loop-invariant operands (valid tid<256)
  const int frow = 8 * rg + (tid >> 5);
  const int fu = 32 * cg + (tid & 31);
  const size_t fyi = (size_t)frow * U + fu;
  const float bh0r = b_h[fu], bh1r = b_h[U + fu], bor = b_out[fu];

  // W base selector for phase P
  auto wbase = [&](int P) -> const float* {
    const int p = P & 3;
    const float* Wsrc = (p == 0)   ? w_y
                        : (p == 3) ? w_out
                                   : w_h + (size_t)(p - 1) * U * U;
    return Wsrc + (size_t)k0 * U + 32 * cg + cb;
  };
  // ---- W prefetch for P=0 (static addresses -> latency off critical path) --
  f4 wreg[32];  // W[k0+j][cb..cb+4), j=0..31
  {
    const float* wp = wbase(0);
#pragma unroll
    for (int j = 0; j < 32; ++j) wreg[j] = *(const f4*)(wp + (size_t)j * U);
  }

  for (int P = 0; P < 4 * T; ++P) {
    const int t = P >> 2, p = P & 3;
    const float* Asrc =
        slots + (size_t)((P + 1) & 1) * BU + (size_t)(8 * rg) * U;
    float* slotw = slots + (size_t)(P & 1) * BU;
    // ---- 0. finalize-operand prefetch (phase-start-known, WG-private /
    //         precomputed; latency hides under poll + stage) ----
    float xpre = 0.f, ypre = 0.f;
    if (tid < 256) {
      if (p == 0) xpre = xp[((size_t)t * B + frow) * U + fu];
      else if (p == 3) ypre = ybuf[fyi];
    }
    float yout = 0.f;  // deferred p3 out-store
    size_t oidx = 0;
    int do_out = 0;
    // ---- 1. acquire: wave0's 32 lanes read 32 producer flags (one 128B
    //         LLC transaction), __all(f>=P); bounded for container safety --
    if (P > 0) {
      if (tid < 64) {
        const unsigned tg = (unsigned)P;
        for (int it = 0; it < (1 << 20); ++it) {
          unsigned f = llc_flag(pollf);
          if (__all((int)(f >= tg))) break;
          __builtin_amdgcn_s_sleep(1);
        }
      }
      __syncthreads();
      asm volatile("" ::: "memory");
    }
    // ---- 2. stage A: 8 rows x 1024, 8B sc1 loads -> single b128 LDS write --
#pragma unroll
    for (int rep = 0; rep < 4; ++rep) {
      int idx4 = 512 * rep + tid;  // f4 index in [0,2048)
      int row = idx4 >> 8, kq = idx4 & 255, k = 4 * kq;
      const float* pa = Asrc + (size_t)row * U + k;
      unsigned long long v0 = llc_load64(pa);
      unsigned long long v1 = llc_load64(pa + 2);
      f4 v;
      ((unsigned long long*)&v)[0] = v0;
      ((unsigned long long*)&v)[1] = v1;
      *(f4*)&a_s[row * APITCH + 36 * (k >> 5) + (k & 31)] = v;
    }
    __syncthreads();
    // ---- 3. main: 4x4x(K=32) tile; A from LDS, W from registers ----
    f4 acc[4];
#pragma unroll
    for (int i = 0; i < 4; ++i) acc[i] = (f4){0.f, 0.f, 0.f, 0.f};
    {
      const int abase = r0 * APITCH + 36 * s;  // 36*(k0>>5) = 36s
#pragma unroll
      for (int q = 0; q < 8; ++q) {
        const int ai = abase + 4 * q;
        f4 a0 = *(const f4*)&a_s[ai];
        f4 a1 = *(const f4*)&a_s[ai + APITCH];
        f4 a2 = *(const f4*)&a_s[ai + 2 * APITCH];
        f4 a3 = *(const f4*)&a_s[ai + 3 * APITCH];
        const f4 w0 = wreg[4 * q], w1 = wreg[4 * q + 1];
        const f4 w2 = wreg[4 * q + 2], w3 = wreg[4 * q + 3];
        acc[0] += a0.x * w0 + a0.y * w1 + a0.z * w2 + a0.w * w3;
        acc[1] += a1.x * w0 + a1.y * w1 + a1.z * w2 + a1.w * w3;
        acc[2] += a2.x * w0 + a2.y * w1 + a2.z * w2 + a2.w * w3;
        acc[3] += a3.x * w0 + a3.y * w1 + a3.z * w2 + a3.w * w3;
      }
    }
    // ---- 4. write partials red2[s*264 + out], b128 (de-aliased: no
    //         pre-barrier needed; prev-phase finalize reads were sealed by
    //         the drain barrier) ----
#pragma unroll
    for (int i = 0; i < 4; ++i)
      *(f4*)&red2[s * RPITCH + (r0 + i) * 32 + cb] = acc[i];
    __syncthreads();  // B1: all partials visible
    // ---- 5. finalize: 256 threads, sum 32 partials, bias+act, store ----
    if (tid < 256) {
      float sum = 0.f;
#pragma unroll
      for (int z = 0; z < 32; ++z) sum += red2[z * RPITCH + tid];
      if (p == 0) {
        float v = sum + xpre;
        llc_store(slotw + fyi, LRELU(v));
      } else if (p < 3) {
        float v = sum + (p == 1 ? bh0r : bh1r);
        llc_store(slotw + fyi, LRELU(v));
      } else {
        float yn = ypre + sum + bor;  // ybuf prefetched at phase start
        ybuf[fyi] = yn;
        llc_store(slotw + fyi, yn);  // y is next p0's A
        yout = yn;                   // out[] store deferred past flag post
        oidx = ((size_t)frow * T + t) * U + fu;
        do_out = 1;
      }
    }
    // ---- 6. drain: exchange stores at LLC before the flag post ----
    asm volatile("" ::: "memory");
    __builtin_amdgcn_s_waitcnt(0);
    __syncthreads();
    // ---- 7. W prefetch for P+1 (single reload site; overlaps post + poll
    //         + next stage) ----
    if (P < 4 * T - 1) {
      const float* wp = wbase(P + 1);
#pragma unroll
      for (int j = 0; j < 32; ++j) wreg[j] = *(const f4*)(wp + (size_t)j * U);
    }
    // ---- 8. release: per-producer flag store (no RMW serialization) ----
    if (tid == 0) llc_flag_store(myflag, (unsigned)(P + 1));
    // ---- 9. deferred p3 out-store (HBM ack off the flag critical path;
    //         next phase's waitcnt(0) absorbs it) ----
    if (do_out) out[oidx] = yout;
  }
}

extern "C" void kernel_launch(void* const* d_in, const int* in_sizes, int n_in,
                              void* d_out, int out_size, void* d_ws,
                              size_t ws_size, hipStream_t stream) {
  const int* x = (const int*)d_in[0];
  const float* emb = (const float*)d_in[1];
  const float* w_y = (const float*)d_in[2];
  const float* w_x = (const float*)d_in[3];
  const float* b_in = (const float*)d_in[4];
  const float* w_h = (const float*)d_in[5];
  const float* b_h = (const float*)d_in[6];
  const float* w_out = (const float*)d_in[7];
  const float* b_out = (const float*)d_in[8];
  const float* h0 = (const float*)d_in[9];
  float* out = (float*)d_out;

  // workspace (floats): xproj | slots[2] | ybuf | flags
  float* ws = (float*)d_ws;
  float* xpb = ws;                         // T*B*U
  float* slots = xpb + (size_t)T * B * U;  // 2*BU
  float* ybuf = slots + 2 * (size_t)BU;    // BU
  unsigned* flags = (unsigned*)(ybuf + (size_t)BU);  // 256 uints (512 zeroed)

  k_init<<<256, 256, 0, stream>>>(slots + (size_t)BU, ybuf, h0, flags);
  dim3 g1(256, 16);
  k_xproj<<<g1, 256, 0, stream>>>(x, emb, w_x, b_in, xpb);

  void* args[] = {&xpb,   &w_y, &w_h,   &b_h,  &w_out,
                  &b_out, &out, &slots, &ybuf, &flags};
  hipLaunchCooperativeKernel((void*)k_seq, dim3(256), dim3(512), args, 0u,
                             stream);
}